// Round 9
// baseline (253.842 us; speedup 1.0000x reference)
//
#include <hip/hip_runtime.h>
#include <math.h>
#include <float.h>

#define NHEAD 16
#define DHEAD 64
#define SEQT  2048
#define NB    2
#define CEMB  1024
#define C3    3072

typedef __attribute__((ext_vector_type(8)))  short s16x8;   // MFMA A/B frag (8 bf16)
typedef __attribute__((ext_vector_type(4)))  short s16x4;
typedef __attribute__((ext_vector_type(4)))  unsigned short u16x4;
typedef __attribute__((ext_vector_type(4)))  float f32x4;
typedef __attribute__((ext_vector_type(16))) float f32x16;

__device__ __forceinline__ float sigmoidf_(float x) { return 1.0f / (1.0f + expf(-x)); }

__device__ __forceinline__ unsigned short f2b(float f) {
    __bf16 b = (__bf16)f;
    return __builtin_bit_cast(unsigned short, b);
}

__device__ __forceinline__ void gload16(const void* g, void* l) {
    __builtin_amdgcn_global_load_lds(
        (const __attribute__((address_space(1))) void*)g,
        (__attribute__((address_space(3))) void*)l, 16, 0, 0);
}

// ---------------------------------------------------------------------------
// fp32 -> bf16 (vectorized)
// ---------------------------------------------------------------------------
__global__ __launch_bounds__(256) void convert_bf16(const float* __restrict__ s,
                                                    unsigned short* __restrict__ d)
{
    int i = (blockIdx.x * 256 + threadIdx.x) * 4;
    float4 v = *reinterpret_cast<const float4*>(s + i);
    u16x4 o = { f2b(v.x), f2b(v.y), f2b(v.z), f2b(v.w) };
    *reinterpret_cast<u16x4*>(d + i) = o;
}

// ---------------------------------------------------------------------------
// transpose + convert: src fp32 [rows][cols] -> dst bf16 [cols][rows]
// ---------------------------------------------------------------------------
__global__ __launch_bounds__(256) void transpose_convert(
    const float* __restrict__ src, unsigned short* __restrict__ dst,
    int rows, int cols)
{
    __shared__ float t[64][65];
    const int tid = threadIdx.x;
    const int c0 = blockIdx.x * 64, r0 = blockIdx.y * 64;
    const int tr = tid >> 4, tc = tid & 15;
#pragma unroll
    for (int l = 0; l < 4; ++l) {
        int r = l * 16 + tr;
        float4 vv = *reinterpret_cast<const float4*>(
            &src[(size_t)(r0 + r) * cols + c0 + tc * 4]);
        t[r][tc * 4 + 0] = vv.x; t[r][tc * 4 + 1] = vv.y;
        t[r][tc * 4 + 2] = vv.z; t[r][tc * 4 + 3] = vv.w;
    }
    __syncthreads();
#pragma unroll
    for (int l = 0; l < 4; ++l) {
        int n = l * 16 + tr;
        u16x4 o4 = { f2b(t[tc * 4 + 0][n]), f2b(t[tc * 4 + 1][n]),
                     f2b(t[tc * 4 + 2][n]), f2b(t[tc * 4 + 3][n]) };
        *reinterpret_cast<u16x4*>(&dst[(size_t)(c0 + n) * rows + r0 + tc * 4]) = o4;
    }
}

// ---------------------------------------------------------------------------
// ltab[h][rel] = log2(mask_pos(rel)*wave(rel)) - 8 ; -1e30 if mask == 0.
// ---------------------------------------------------------------------------
__global__ void build_ltab(const float* __restrict__ sp, const float* __restrict__ pw,
                           const float* __restrict__ rw, float* __restrict__ ltab)
{
    const int h = blockIdx.x;
    const float span   = sigmoidf_(sp[h]) * 2048.0f;
    const float period = 2.0f + 2.0f * sigmoidf_(pw[h]);
    const float ratio  = -0.25f + 0.5f * sigmoidf_(rw[h]);
    const float amp    = period * 0.25f;
    const float off    = period * ratio;
    for (int rel = threadIdx.x; rel < SEQT; rel += blockDim.x) {
        float mp = fminf(fmaxf((32.0f - (float)rel + span) * 0.03125f, 0.0f), 1.0f);
        float wv = 0.5f * (cosf(6.283185307179586f * (float)rel / period) + 1.0f) * amp
                   + 0.5f + off;
        wv = fminf(fmaxf(wv, 0.0f), 1.0f);
        float m = mp * wv;
        ltab[h * SEQT + rel] = (m > 0.0f) ? (log2f(m) - 8.0f) : -1e30f;
    }
}

// ---------------------------------------------------------------------------
// MFMA GEMM (unchanged, R7/R8-verified): tile 128x128, BK=64, 256 thr.
// ---------------------------------------------------------------------------
template<int N_, int MODE>
__global__ __launch_bounds__(256) void mfma_gemm(
    const unsigned short* __restrict__ A, const unsigned short* __restrict__ Wt,
    const float* __restrict__ bias, float* __restrict__ outf,
    unsigned short* __restrict__ qo, unsigned short* __restrict__ ko,
    unsigned short* __restrict__ vo)
{
    __shared__ unsigned short As[128 * 64];
    __shared__ unsigned short Bs[128 * 64];
    char* AsB = (char*)As;
    char* BsB = (char*)Bs;

    const int tid  = threadIdx.x;
    const int lane = tid & 63;
    const int wid  = tid >> 6;
    const int wm   = wid >> 1, wn = wid & 1;
    const int g    = lane >> 4, l15 = lane & 15;
    const int m0   = blockIdx.y * 128, n0 = blockIdx.x * 128;

    const int srow = lane >> 3;
    const int skel = 8 * ((lane & 7) ^ srow);
    const int swz  = (lane & 7) << 4;

    f32x4 acc[4][4];
#pragma unroll
    for (int i = 0; i < 4; ++i)
#pragma unroll
        for (int j = 0; j < 4; ++j) acc[i][j] = (f32x4){0.f, 0.f, 0.f, 0.f};

    for (int kt = 0; kt < 16; ++kt) {
        const int k0 = kt * 64;
#pragma unroll
        for (int it = 0; it < 4; ++it) {
            int cc = wid * 4 + it;
            int row = cc * 8 + srow;
            gload16(A  + (size_t)(m0 + row) * 1024 + k0 + skel, AsB + cc * 1024);
            gload16(Wt + (size_t)(n0 + row) * 1024 + k0 + skel, BsB + cc * 1024);
        }
        __syncthreads();
#pragma unroll
        for (int kk = 0; kk < 2; ++kk) {
            s16x8 af[4], bfr[4];
#pragma unroll
            for (int mf = 0; mf < 4; ++mf) {
                int m = wm * 64 + mf * 16 + l15;
                af[mf] = *reinterpret_cast<const s16x8*>(
                    AsB + m * 128 + ((kk * 64 + g * 16) ^ swz));
            }
#pragma unroll
            for (int nf = 0; nf < 4; ++nf) {
                int n = wn * 64 + nf * 16 + l15;
                bfr[nf] = *reinterpret_cast<const s16x8*>(
                    BsB + n * 128 + ((kk * 64 + g * 16) ^ swz));
            }
#pragma unroll
            for (int mf = 0; mf < 4; ++mf)
#pragma unroll
                for (int nf = 0; nf < 4; ++nf)
                    acc[mf][nf] = __builtin_amdgcn_mfma_f32_16x16x32_bf16(
                        af[mf], bfr[nf], acc[mf][nf], 0, 0, 0);
        }
        __syncthreads();
    }

#pragma unroll
    for (int mf = 0; mf < 4; ++mf)
#pragma unroll
        for (int nf = 0; nf < 4; ++nf) {
            const int n = n0 + wn * 64 + nf * 16 + l15;
            const int mb = m0 + wm * 64 + mf * 16 + 4 * g;
            const float bs = bias[n];
            if (MODE == 0) {
                const int which = n >> 10;
                const int cc = n & 1023;
                const int hh = cc >> 6, dd = cc & 63;
                const int t0 = mb & (SEQT - 1);
                const int bb = mb >> 11;
                if (which == 2) {
                    u16x4 pk;
#pragma unroll
                    for (int r = 0; r < 4; ++r) pk[r] = f2b(acc[mf][nf][r] + bs);
                    *reinterpret_cast<u16x4*>(
                        &vo[(((size_t)bb * NHEAD + hh) * DHEAD + dd) * SEQT + t0]) = pk;
                } else {
                    unsigned short* dst = (which == 0) ? qo : ko;
#pragma unroll
                    for (int r = 0; r < 4; ++r)
                        dst[(((size_t)bb * NHEAD + hh) * SEQT + t0 + r) * DHEAD + dd] =
                            f2b(acc[mf][nf][r] + bs);
                }
            } else {
#pragma unroll
                for (int r = 0; r < 4; ++r)
                    outf[(size_t)(mb + r) * N_ + n] = acc[mf][nf][r] + bs;
            }
        }
}

// ---------------------------------------------------------------------------
// MFMA flash attention — R9: 32x32x16 MFMA structure.
//  - 4 waves x 32 q-rows = 128-row Q-block; KV tile 64; 512 blocks.
//  - swapped QK^T: S^T C/D (col=lane&31=query, row=key=(r&3)+8*(r>>2)+4*hi)
//    makes P lane-local; PV A-frag (t,n) = S-tile-t regs [8n..8n+7] (derived),
//    V-side matched with two ds_read_b64 per MFMA. No cross-lane P movement.
//  - fixed-shift softmax (M=8 in ltab), per-lane denominator + one shfl_xor.
//  - XCD pin (4 bh/XCD) + zigzag qt remap for CU load balance.
//  - 2-phase double-buffered K/V staging; per-wave activity guard.
// ---------------------------------------------------------------------------
__global__ __launch_bounds__(256) void attn_mfma(
    const unsigned short* __restrict__ q, const unsigned short* __restrict__ k,
    const unsigned short* __restrict__ vt, const float* __restrict__ ltab,
    const float* __restrict__ span_p, unsigned short* __restrict__ y)
{
    __shared__ unsigned short Ks[2][64 * 64];   // [key][d], swizzled 16B chunks
    __shared__ unsigned short Vs[2][64 * 64];   // [d][key], swizzled 16B chunks

    const int tid  = threadIdx.x;
    const int lane = tid & 63;
    const int w    = tid >> 6;
    const int q31  = lane & 31, hi = lane >> 5;

    // XCD pin + zigzag balance remap (512 = 8 xcd * 4 bh * 16 qt, bijective)
    const int wgid = blockIdx.x + gridDim.x * blockIdx.y;
    const int xcd  = wgid & 7;
    const int li   = wgid >> 3;
    const int bhl  = li >> 4;
    const int i2   = ((li & 15) + 4 * bhl) & 15;
    const int qt   = (i2 & 1) ? (15 - (i2 >> 1)) : (i2 >> 1);
    const int bh   = bhl * 8 + xcd;
    const int q0   = qt * 128;
    const int b    = bh >> 4, h = bh & 15;

    const float span = sigmoidf_(span_p[h]) * 2048.0f;
    const float thr  = 32.0f + span;
    const float* lt  = ltab + h * SEQT;

    const size_t base = (size_t)bh * SEQT * DHEAD;
    const unsigned short* kb  = k  + base;
    const unsigned short* vtb = vt + base;

    const int qbase = q0 + 32 * w;

    // Q frags (B operand): col = q31, k-chunk c: d = 16c + 8hi + 0..7
    s16x8 qa[4];
    {
        const char* qrow = (const char*)(q + base + (size_t)(qbase + q31) * DHEAD);
#pragma unroll
        for (int c = 0; c < 4; ++c)
            qa[c] = *reinterpret_cast<const s16x8*>(qrow + c * 32 + hi * 16);
    }

    f32x16 oa0, oa1;
#pragma unroll
    for (int i = 0; i < 16; ++i) { oa0[i] = 0.f; oa1[i] = 0.f; }
    float lrp = 0.f;

    const int srow = lane >> 3;
    const int skel = 8 * ((lane & 7) ^ srow);   // inverse-swizzled global src
    const int swz  = (lane & 7) << 4;           // read-side XOR (row&7==lane&7)
    const float SCL = 0.18033688f;              // 0.125 * log2(e)

    int jstart = 0;
    {   float lim = (float)(q0 - 63) - thr;     // tiles j0 <= lim fully masked
        if (lim >= 0.0f) jstart = (((int)lim) >> 6) * 64 + 64; }

    auto STAGE = [&](int bsel, int j0s) {
#pragma unroll
        for (int it = 0; it < 2; ++it) {
            int cc = w * 2 + it;
            gload16(kb  + (size_t)(j0s + cc * 8 + srow) * DHEAD + skel,
                    (char*)Ks[bsel] + cc * 1024);
            gload16(vtb + (size_t)(cc * 8 + srow) * SEQT + j0s + skel,
                    (char*)Vs[bsel] + cc * 1024);
        }
    };

    STAGE(0, jstart);
    __syncthreads();
    int cur = 0;

    const int jend = q0 + 64;                   // last tile (covers q0+127 rows)
    for (int j0 = jstart; j0 <= jend; j0 += 64) {
        if (j0 < jend) STAGE(cur ^ 1, j0 + 64);

        // per-wave guard: any causal overlap AND not fully span-masked
        const bool active = (j0 <= qbase + 31) &&
                            ((float)(qbase - j0 - 63) < thr);
        if (active) {
            // ---- S^T: st[t][r] = S[key j0+32t+(r&3)+8*(r>>2)+4hi][qbase+q31]
            f32x16 st0, st1;
#pragma unroll
            for (int i = 0; i < 16; ++i) { st0[i] = 0.f; st1[i] = 0.f; }
#pragma unroll
            for (int c = 0; c < 4; ++c) {
                const int dof = (c * 32 + hi * 16) ^ swz;
                s16x8 kf0 = *reinterpret_cast<const s16x8*>(
                    (const char*)Ks[cur] + q31 * 128 + dof);
                s16x8 kf1 = *reinterpret_cast<const s16x8*>(
                    (const char*)Ks[cur] + (32 + q31) * 128 + dof);
                st0 = __builtin_amdgcn_mfma_f32_32x32x16_bf16(kf0, qa[c], st0, 0, 0, 0);
                st1 = __builtin_amdgcn_mfma_f32_32x32x16_bf16(kf1, qa[c], st1, 0, 0, 0);
            }

            // ---- p = exp2(s*SCL + lt[rel]); rel<0 or masked -> exact 0
            const int relq = qbase + q31 - j0 - 4 * hi;
            float p0[16], p1[16];
            float lacc = 0.f;
#pragma unroll
            for (int r = 0; r < 16; ++r) {
                int koff = (r & 3) + 8 * (r >> 2);
                int rel0 = relq - koff;
                int rel1 = rel0 - 32;
                float a0 = 0.f, a1 = 0.f;
                if (rel0 >= 0) a0 = exp2f(fmaf(st0[r], SCL, lt[rel0]));
                if (rel1 >= 0) a1 = exp2f(fmaf(st1[r], SCL, lt[rel1]));
                p0[r] = a0; p1[r] = a1;
                lacc += a0 + a1;
            }
            lrp += lacc;

            // ---- PV A-frags: pa[t][n][e] = bf16(p_t[8n+e])  (register-only)
            s16x8 pa00, pa01, pa10, pa11;
#pragma unroll
            for (int e = 0; e < 8; ++e) {
                pa00[e] = (short)f2b(p0[e]);
                pa01[e] = (short)f2b(p0[8 + e]);
                pa10[e] = (short)f2b(p1[e]);
                pa11[e] = (short)f2b(p1[8 + e]);
            }

            // ---- O += P V : B elem(hi,e) = V[32t+16n+8(e>>2)+4hi+(e&3)][d]
#pragma unroll
            for (int td = 0; td < 2; ++td) {
                const char* vrow = (const char*)Vs[cur] + (32 * td + q31) * 128;
                f32x16 oo = td ? oa1 : oa0;
#pragma unroll
                for (int t = 0; t < 2; ++t)
#pragma unroll
                    for (int n = 0; n < 2; ++n) {
                        int bse = 64 * t + 32 * n + 8 * hi;
                        s16x4 lo4 = *reinterpret_cast<const s16x4*>(vrow + (bse ^ swz));
                        s16x4 hi4 = *reinterpret_cast<const s16x4*>(vrow + ((bse | 16) ^ swz));
                        s16x8 vf;
#pragma unroll
                        for (int e = 0; e < 4; ++e) { vf[e] = lo4[e]; vf[4 + e] = hi4[e]; }
                        s16x8 paf = t ? (n ? pa11 : pa10) : (n ? pa01 : pa00);
                        oo = __builtin_amdgcn_mfma_f32_32x32x16_bf16(paf, vf, oo, 0, 0, 0);
                    }
                if (td) oa1 = oo; else oa0 = oo;
            }
        }

        __syncthreads();            // drains prefetch vmcnt + guards buffer reuse
        cur ^= 1;
    }

    // ---- denominator + store: O C/D row = (r&3)+8*(r>>2)+4hi, col = q31
    float lf = lrp + __shfl_xor(lrp, 32, 64);   // lanes qq & qq+32 -> full l[qq]

    unsigned short* yb = y + (size_t)b * SEQT * CEMB + h * 64;
#pragma unroll
    for (int r = 0; r < 16; ++r) {
        int qrow = (r & 3) + 8 * (r >> 2) + 4 * hi;
        float inv = 1.0f / __shfl(lf, qrow, 64);
        size_t rowoff = (size_t)(qbase + qrow) * CEMB;
        yb[rowoff + q31]      = f2b(oa0[r] * inv);
        yb[rowoff + 32 + q31] = f2b(oa1[r] * inv);
    }
}

// ---------------------------------------------------------------------------
// span loss
// ---------------------------------------------------------------------------
__global__ void span_loss_kernel(const float* __restrict__ sp,
                                 const float* __restrict__ pw,
                                 const float* __restrict__ rw,
                                 float* __restrict__ out)
{
    int lane = threadIdx.x;
    float val = 0.f;
    if (lane < NHEAD) {
        float span   = sigmoidf_(sp[lane]) * 2048.0f;
        float period = 2.0f + 2.0f * sigmoidf_(pw[lane]);
        float ratio  = -0.25f + 0.5f * sigmoidf_(rw[lane]);
        float ltm = 1.0f / period + 2.0f * ratio - 0.25f + 0.5f;
        val = (span + 32.0f) * ltm;
    }
#pragma unroll
    for (int o = 1; o < 16; o <<= 1) val += __shfl_xor(val, o, 64);
    if (lane == 0) out[0] = 2e-6f * val / 16.0f;
}

// ---------------------------------------------------------------------------
extern "C" void kernel_launch(void* const* d_in, const int* in_sizes, int n_in,
                              void* d_out, int out_size, void* d_ws, size_t ws_size,
                              hipStream_t stream)
{
    const float* x        = (const float*)d_in[0];
    const float* w_attn   = (const float*)d_in[1];
    const float* b_attn   = (const float*)d_in[2];
    const float* w_proj   = (const float*)d_in[3];
    const float* b_proj   = (const float*)d_in[4];
    const float* span_p   = (const float*)d_in[5];
    const float* period_w = (const float*)d_in[6];
    const float* ratio_w  = (const float*)d_in[7];

    char* ws = (char*)d_ws;
    unsigned short* xb  = (unsigned short*)(ws);                      // 8 MB [4096][1024]
    unsigned short* wT  = (unsigned short*)(ws + ((size_t)8  << 20)); // 6 MB [3072][1024]
    unsigned short* wpT = (unsigned short*)(ws + ((size_t)14 << 20)); // 2 MB [1024][1024]
    unsigned short* qb  = (unsigned short*)(ws + ((size_t)16 << 20)); // 8 MB [B,H,T,D]
    unsigned short* kb  = (unsigned short*)(ws + ((size_t)24 << 20)); // 8 MB [B,H,T,D]
    unsigned short* vt  = (unsigned short*)(ws + ((size_t)32 << 20)); // 8 MB [B,H,D,T]
    float*          lt  = (float*)         (ws + ((size_t)40 << 20)); // 128 KB [16][2048]
    unsigned short* y1  = xb;   // xb dead after QKV GEMM — alias

    float* out = (float*)d_out;
    const size_t PLANE = (size_t)NB * SEQT * CEMB;       // 4,194,304

    convert_bf16<<<4096, 256, 0, stream>>>(x, xb);
    transpose_convert<<<dim3(C3 / 64, CEMB / 64), 256, 0, stream>>>(w_attn, wT, CEMB, C3);
    transpose_convert<<<dim3(CEMB / 64, CEMB / 64), 256, 0, stream>>>(w_proj, wpT, CEMB, CEMB);
    build_ltab<<<NHEAD, 256, 0, stream>>>(span_p, period_w, ratio_w, lt);

    mfma_gemm<C3, 0><<<dim3(C3 / 128, (NB * SEQT) / 128), 256, 0, stream>>>(
        xb, wT, b_attn, nullptr, qb, kb, vt);

    attn_mfma<<<dim3(SEQT / 128, NB * NHEAD), 256, 0, stream>>>(
        qb, kb, vt, lt, span_p, y1);

    mfma_gemm<CEMB, 1><<<dim3(CEMB / 128, (NB * SEQT) / 128), 256, 0, stream>>>(
        y1, wpT, b_proj, out, nullptr, nullptr, nullptr);

    span_loss_kernel<<<1, 64, 0, stream>>>(span_p, period_w, ratio_w, out + PLANE);
}